// Round 2
// baseline (392.037 us; speedup 1.0000x reference)
//
#include <hip/hip_runtime.h>

#define N1 8192
#define N2 8192
#define DIM 256
#define TILE 128
#define BK 32
#define KITERS (DIM / BK)   // 8

typedef _Float16 half8 __attribute__((ext_vector_type(8)));
typedef _Float16 half4v __attribute__((ext_vector_type(4)));
typedef float f32x4 __attribute__((ext_vector_type(4)));

// --- Kernel 1: column mean of x1 (adj pre-zeroed). 512 blocks x 16 rows. ---
__global__ __launch_bounds__(256) void colmean_kernel(const float* __restrict__ x1,
                                                      float* __restrict__ adj) {
    int t = threadIdx.x;                  // dim index 0..255 (coalesced per row)
    size_t r0 = (size_t)blockIdx.x * 16;
    float s = 0.f;
    #pragma unroll
    for (int r = 0; r < 16; ++r) s += x1[(r0 + r) * DIM + t];
    atomicAdd(&adj[t], s * (1.0f / (float)N1));
}

// --- Kernel 2: center/scale/quantize to fp16 + row sq-norms. One wave per row. ---
__global__ __launch_bounds__(256) void quant_kernel(
    const float* __restrict__ x1, const float* __restrict__ x2,
    const float* __restrict__ adj, const float* __restrict__ ls,
    _Float16* __restrict__ y1, _Float16* __restrict__ y2,
    float* __restrict__ sq1, float* __restrict__ sq2) {
    int wave = threadIdx.x >> 6, lane = threadIdx.x & 63;
    int grow = blockIdx.x * 4 + wave;
    const float* x; _Float16* y; float* sq; int row;
    if (grow < N1) { x = x1; y = y1; sq = sq1; row = grow; }
    else           { x = x2; y = y2; sq = sq2; row = grow - N1; }
    int c = lane * 4;
    f32x4 xv = *(const f32x4*)&x[(size_t)row * DIM + c];
    f32x4 av = *(const f32x4*)&adj[c];
    f32x4 lv = *(const f32x4*)&ls[c];
    half4v h;
    float p = 0.f;
    #pragma unroll
    for (int u = 0; u < 4; ++u) {
        float v = (xv[u] - av[u]) / lv[u];
        _Float16 hh = (_Float16)v;
        h[u] = hh;
        float f = (float)hh;
        p += f * f;
    }
    *(half4v*)&y[(size_t)row * DIM + c] = h;
    #pragma unroll
    for (int off = 32; off > 0; off >>= 1) p += __shfl_down(p, off, 64);
    if (lane == 0) sq[row] = p;
}

// --- Kernel 3: LDS-free MFMA GEMM + fused Matern epilogue ---
// K=256 and y1+y2=8MB (L2-resident) make LDS staging pure overhead (barrier
// vmcnt drains + ds traffic to cache already-cached data). Each lane loads its
// MFMA fragments directly from global: 16 rows x 64B segments per instruction,
// served by L1/L2 (waves 0,1 share A rows; waves 0,2 share B rows; kt pairs
// share 128B lines). No __syncthreads anywhere -> compiler pipelines next-kt
// loads under current-kt MFMAs with counted vmcnt.
// MFMA issued as mfma(b, a): D has col(lane&15)=M, rows((lane>>4)*4+reg)=4
// consecutive N -> f32x4 epilogue stores.
__global__ __launch_bounds__(256) void matern_gemm(
    const _Float16* __restrict__ y1, const _Float16* __restrict__ y2,
    const float* __restrict__ sq1, const float* __restrict__ sq2,
    float* __restrict__ out) {
    const int tid  = threadIdx.x;
    const int wave = tid >> 6;
    const int lane = tid & 63;
    const int row0 = blockIdx.x * TILE;  // M offset (x1 rows)
    const int col0 = blockIdx.y * TILE;  // N offset (x2 rows)
    const int wm = (wave >> 1) * 64;     // 2x2 wave grid, 64x64 per wave
    const int wn = (wave & 1) * 64;
    const int fm = lane & 15;            // fragment row within 16-row subtile
    const int hq = lane >> 4;            // k-chunk (0..3), 8 fp16 each

    const _Float16* Abase = y1 + (size_t)(row0 + wm + fm) * DIM + hq * 8;
    const _Float16* Bbase = y2 + (size_t)(col0 + wn + fm) * DIM + hq * 8;

    f32x4 acc[4][4];
    const f32x4 zero = {0.f, 0.f, 0.f, 0.f};
    #pragma unroll
    for (int i = 0; i < 4; ++i)
        #pragma unroll
        for (int j = 0; j < 4; ++j) acc[i][j] = zero;

    // 2-stage register pipeline, fully unrolled (all indices compile-time).
    half8 a[2][4], b[2][4];
    #pragma unroll
    for (int t = 0; t < 4; ++t) {
        a[0][t] = *(const half8*)(Abase + (size_t)t * 16 * DIM);
        b[0][t] = *(const half8*)(Bbase + (size_t)t * 16 * DIM);
    }
    #pragma unroll
    for (int kt = 0; kt < KITERS; ++kt) {
        const int c = kt & 1;
        if (kt + 1 < KITERS) {
            const int kof = (kt + 1) * BK;   // halves; 64B per kt step
            #pragma unroll
            for (int t = 0; t < 4; ++t) {
                a[c ^ 1][t] = *(const half8*)(Abase + (size_t)t * 16 * DIM + kof);
                b[c ^ 1][t] = *(const half8*)(Bbase + (size_t)t * 16 * DIM + kof);
            }
        }
        #pragma unroll
        for (int i = 0; i < 4; ++i)
            #pragma unroll
            for (int j = 0; j < 4; ++j)
                acc[i][j] = __builtin_amdgcn_mfma_f32_16x16x32_f16(b[c][j], a[c][i], acc[i][j], 0, 0, 0);
    }

    // Epilogue: swapped-operand C/D layout: col(lane&15)=M, row((lane>>4)*4+reg)=N.
    const int em = lane & 15;        // M within 16-subtile
    const int en = hq * 4;           // N base within 16-subtile (4 consecutive via reg)
    float s1v[4];
    #pragma unroll
    for (int i = 0; i < 4; ++i)
        s1v[i] = sq1[row0 + wm + i * 16 + em];
    f32x4 s2v[4];
    #pragma unroll
    for (int j = 0; j < 4; ++j)
        s2v[j] = *(const f32x4*)&sq2[col0 + wn + j * 16 + en];

    #pragma unroll
    for (int i = 0; i < 4; ++i) {
        float* rowp = out + (size_t)(row0 + wm + i * 16 + em) * N2 + (col0 + wn + en);
        #pragma unroll
        for (int j = 0; j < 4; ++j) {   // stores use imm offsets j*64B
            f32x4 o;
            #pragma unroll
            for (int r = 0; r < 4; ++r) {
                float d2 = s1v[i] + s2v[j][r] - 2.0f * acc[i][j][r];
                // fmax(1e-30) subsumes both clamp(d2,0) and clamp(dist,1e-15):
                // dist = d2 * rsqrt(d2) >= 1e-15, and never NaN.
                d2 = fmaxf(d2, 1e-30f);
                float dist = d2 * __frsqrt_rn(d2);
                float t3 = 1.7320508075688772f * dist;
                o[r] = (1.0f + t3) * __expf(-t3);
            }
            *(f32x4*)&rowp[j * 16] = o;
        }
    }
}

extern "C" void kernel_launch(void* const* d_in, const int* in_sizes, int n_in,
                              void* d_out, int out_size, void* d_ws, size_t ws_size,
                              hipStream_t stream) {
    const float* x1 = (const float*)d_in[0];
    const float* x2 = (const float*)d_in[1];
    const float* ls = (const float*)d_in[2];
    float* out = (float*)d_out;

    // workspace: adj[256]f32 | sq1[8192]f32 | sq2[8192]f32 | y1 fp16 4MB | y2 fp16 4MB
    char* ws = (char*)d_ws;
    float* adj = (float*)ws;
    float* sq1 = (float*)(ws + 1024);
    float* sq2 = (float*)(ws + 1024 + 32768);
    _Float16* y1 = (_Float16*)(ws + 66560);
    _Float16* y2 = (_Float16*)(ws + 66560 + 4194304);

    hipMemsetAsync(adj, 0, 256 * sizeof(float), stream);
    colmean_kernel<<<N1 / 16, 256, 0, stream>>>(x1, adj);
    quant_kernel<<<(N1 + N2) / 4, 256, 0, stream>>>(x1, x2, adj, ls, y1, y2, sq1, sq2);
    matern_gemm<<<dim3(N1 / TILE, N2 / TILE), 256, 0, stream>>>(y1, y2, sq1, sq2, out);
}

// Round 3
// 349.856 us; speedup vs baseline: 1.1206x; 1.1206x over previous
//
#include <hip/hip_runtime.h>

#define N1 8192
#define N2 8192
#define DIM 256
#define TILE 128
#define BK 32
#define KITERS (DIM / BK)   // 8

typedef _Float16 half8 __attribute__((ext_vector_type(8)));
typedef _Float16 half4v __attribute__((ext_vector_type(4)));
typedef float f32x4 __attribute__((ext_vector_type(4)));

// Async global->LDS, 16B per lane. LDS dest is wave-uniform base + lane*16.
__device__ __forceinline__ void async_load16(const void* g, void* lds) {
    __builtin_amdgcn_global_load_lds(
        (__attribute__((address_space(1))) void*)g,
        (__attribute__((address_space(3))) void*)lds,
        16, 0, 0);
}

// --- Kernel 1: column mean of x1 (adj pre-zeroed). 512 blocks x 16 rows. ---
__global__ __launch_bounds__(256) void colmean_kernel(const float* __restrict__ x1,
                                                      float* __restrict__ adj) {
    int t = threadIdx.x;                  // dim index 0..255 (coalesced per row)
    size_t r0 = (size_t)blockIdx.x * 16;
    float s = 0.f;
    #pragma unroll
    for (int r = 0; r < 16; ++r) s += x1[(r0 + r) * DIM + t];
    atomicAdd(&adj[t], s * (1.0f / (float)N1));
}

// --- Kernel 2: center/scale/quantize to fp16 + row sq-norms. One wave per row. ---
__global__ __launch_bounds__(256) void quant_kernel(
    const float* __restrict__ x1, const float* __restrict__ x2,
    const float* __restrict__ adj, const float* __restrict__ ls,
    _Float16* __restrict__ y1, _Float16* __restrict__ y2,
    float* __restrict__ sq1, float* __restrict__ sq2) {
    int wave = threadIdx.x >> 6, lane = threadIdx.x & 63;
    int grow = blockIdx.x * 4 + wave;
    const float* x; _Float16* y; float* sq; int row;
    if (grow < N1) { x = x1; y = y1; sq = sq1; row = grow; }
    else           { x = x2; y = y2; sq = sq2; row = grow - N1; }
    int c = lane * 4;
    f32x4 xv = *(const f32x4*)&x[(size_t)row * DIM + c];
    f32x4 av = *(const f32x4*)&adj[c];
    f32x4 lv = *(const f32x4*)&ls[c];
    half4v h;
    float p = 0.f;
    #pragma unroll
    for (int u = 0; u < 4; ++u) {
        float v = (xv[u] - av[u]) / lv[u];
        _Float16 hh = (_Float16)v;
        h[u] = hh;
        float f = (float)hh;
        p += f * f;
    }
    *(half4v*)&y[(size_t)row * DIM + c] = h;
    #pragma unroll
    for (int off = 32; off > 0; off >>= 1) p += __shfl_down(p, off, 64);
    if (lane == 0) sq[row] = p;
}

// --- Kernel 3: 128x128 tile MFMA GEMM, double-buffered LDS, fused Matern epilogue ---
// Round-0 structure (known-good 327us) + occupancy squeeze:
//   __launch_bounds__(256,4) caps VGPR at 128 -> 4 blocks/CU (was ~2). The
//   2-phase loop's per-iter vmcnt(0) barrier drain (~300cy load latency vs
//   ~100cy of MFMA) is then hidden by other resident blocks (m114 overlap).
//   In-loop live set kept small: all a[0..3] (16 VGPR) but b loaded one at a
//   time in a j-outer MFMA order (4 VGPR), acc 64, addr ~20 -> ~105 < 128.
// MFMA issued as mfma(b, a): D col(lane&15)=M, rows((lane>>4)*4+reg)=4
// consecutive N -> f32x4 epilogue stores (no nontemporal: let L2 write-combine).
__global__ __launch_bounds__(256, 4) void matern_gemm(
    const _Float16* __restrict__ y1, const _Float16* __restrict__ y2,
    const float* __restrict__ sq1, const float* __restrict__ sq2,
    float* __restrict__ out) {
    __shared__ __align__(16) _Float16 As[2][TILE * BK];
    __shared__ __align__(16) _Float16 Bs[2][TILE * BK];

    const int tid  = threadIdx.x;
    const int wave = tid >> 6;
    const int lane = tid & 63;
    const int row0 = blockIdx.x * TILE;  // M offset (x1 rows)
    const int col0 = blockIdx.y * TILE;  // N offset (x2 rows)
    const int wm = (wave >> 1) * 64;     // 2x2 wave grid, 64x64 per wave
    const int wn = (wave & 1) * 64;
    const int fm = lane & 15;            // frag row within 16-row subtile
    const int fk = (lane >> 4) * 8;      // k-chunk base (8 fp16)

    // staging: 512 16B-chunks per tile, 2 per thread; chunk c -> row c>>2, k (c&3)*8
    const int c0 = wave * 128 + lane;
    const int c1 = c0 + 64;
    const int r0c = c0 >> 2, k0c = (c0 & 3) * 8;
    const int r1c = c1 >> 2, k1c = (c1 & 3) * 8;
    const int base0 = (wave * 128) * 16;       // wave-uniform LDS byte base
    const int base1 = base0 + 64 * 16;

    f32x4 acc[4][4];
    const f32x4 zero = {0.f, 0.f, 0.f, 0.f};
    #pragma unroll
    for (int i = 0; i < 4; ++i)
        #pragma unroll
        for (int j = 0; j < 4; ++j) acc[i][j] = zero;

    auto stage = [&](int kt, int buf) {
        const int k = kt * BK;
        async_load16(y1 + (size_t)(row0 + r0c) * DIM + k + k0c, (char*)As[buf] + base0);
        async_load16(y1 + (size_t)(row0 + r1c) * DIM + k + k1c, (char*)As[buf] + base1);
        async_load16(y2 + (size_t)(col0 + r0c) * DIM + k + k0c, (char*)Bs[buf] + base0);
        async_load16(y2 + (size_t)(col0 + r1c) * DIM + k + k1c, (char*)Bs[buf] + base1);
    };

    stage(0, 0);
    int cur = 0;
    #pragma unroll
    for (int kt = 0; kt < KITERS; ++kt) {
        // Single barrier per iter: drains vmcnt (tile kt staged, issued one full
        // compute-phase ago) and fences iter kt-1's LDS reads.
        __syncthreads();
        if (kt + 1 < KITERS) stage(kt + 1, cur ^ 1);

        half8 a[4];
        #pragma unroll
        for (int t = 0; t < 4; ++t)
            a[t] = *(const half8*)&As[cur][(wm + t * 16 + fm) * BK + fk];
        #pragma unroll
        for (int j = 0; j < 4; ++j) {
            half8 b = *(const half8*)&Bs[cur][(wn + j * 16 + fm) * BK + fk];
            #pragma unroll
            for (int i = 0; i < 4; ++i)
                acc[i][j] = __builtin_amdgcn_mfma_f32_16x16x32_f16(b, a[i], acc[i][j], 0, 0, 0);
        }
        cur ^= 1;
    }

    // Epilogue: swapped-operand C/D layout: col(lane&15)=M, row((lane>>4)*4+reg)=N.
    const int em = lane & 15;            // M within 16-subtile
    const int en = (lane >> 4) * 4;      // N base within 16-subtile (4 consecutive via reg)
    float s1v[4];
    #pragma unroll
    for (int i = 0; i < 4; ++i)
        s1v[i] = sq1[row0 + wm + i * 16 + em];
    f32x4 s2v[4];
    #pragma unroll
    for (int j = 0; j < 4; ++j)
        s2v[j] = *(const f32x4*)&sq2[col0 + wn + j * 16 + en];

    #pragma unroll
    for (int i = 0; i < 4; ++i) {
        float* rowp = out + (size_t)(row0 + wm + i * 16 + em) * N2 + (col0 + wn + en);
        #pragma unroll
        for (int j = 0; j < 4; ++j) {   // stores use imm offsets j*64B
            f32x4 o;
            #pragma unroll
            for (int r = 0; r < 4; ++r) {
                float d2 = s1v[i] + s2v[j][r] - 2.0f * acc[i][j][r];
                // fmax(1e-30) subsumes both clamp(d2,0) and clamp(dist,1e-15):
                // dist = d2 * rsqrt(d2) >= 1e-15, and never NaN.
                d2 = fmaxf(d2, 1e-30f);
                float dist = d2 * __frsqrt_rn(d2);
                float t3 = 1.7320508075688772f * dist;
                o[r] = (1.0f + t3) * __expf(-t3);
            }
            *(f32x4*)&rowp[j * 16] = o;
        }
    }
}

extern "C" void kernel_launch(void* const* d_in, const int* in_sizes, int n_in,
                              void* d_out, int out_size, void* d_ws, size_t ws_size,
                              hipStream_t stream) {
    const float* x1 = (const float*)d_in[0];
    const float* x2 = (const float*)d_in[1];
    const float* ls = (const float*)d_in[2];
    float* out = (float*)d_out;

    // workspace: adj[256]f32 | sq1[8192]f32 | sq2[8192]f32 | y1 fp16 4MB | y2 fp16 4MB
    char* ws = (char*)d_ws;
    float* adj = (float*)ws;
    float* sq1 = (float*)(ws + 1024);
    float* sq2 = (float*)(ws + 1024 + 32768);
    _Float16* y1 = (_Float16*)(ws + 66560);
    _Float16* y2 = (_Float16*)(ws + 66560 + 4194304);

    hipMemsetAsync(adj, 0, 256 * sizeof(float), stream);
    colmean_kernel<<<N1 / 16, 256, 0, stream>>>(x1, adj);
    quant_kernel<<<(N1 + N2) / 4, 256, 0, stream>>>(x1, x2, adj, ls, y1, y2, sq1, sq2);
    matern_gemm<<<dim3(N1 / TILE, N2 / TILE), 256, 0, stream>>>(y1, y2, sq1, sq2, out);
}

// Round 4
// 324.263 us; speedup vs baseline: 1.2090x; 1.0789x over previous
//
#include <hip/hip_runtime.h>

#define N1 8192
#define N2 8192
#define DIM 256
#define BM 256           // tile M = tile N = 256
#define KH 64            // halves per K-step (BK)
#define KSTEPS (DIM / KH)   // 4

typedef _Float16 half8 __attribute__((ext_vector_type(8)));
typedef _Float16 half4v __attribute__((ext_vector_type(4)));
typedef float f32x4 __attribute__((ext_vector_type(4)));

// Async global->LDS, 16B per lane. LDS dest is wave-uniform base + lane*16.
__device__ __forceinline__ void async_load16(const void* g, void* lds) {
    __builtin_amdgcn_global_load_lds(
        (__attribute__((address_space(1))) void*)g,
        (__attribute__((address_space(3))) void*)lds,
        16, 0, 0);
}

// --- Kernel 1: column mean of x1 (adj pre-zeroed). 512 blocks x 16 rows. ---
__global__ __launch_bounds__(256) void colmean_kernel(const float* __restrict__ x1,
                                                      float* __restrict__ adj) {
    int t = threadIdx.x;                  // dim index 0..255 (coalesced per row)
    size_t r0 = (size_t)blockIdx.x * 16;
    float s = 0.f;
    #pragma unroll
    for (int r = 0; r < 16; ++r) s += x1[(r0 + r) * DIM + t];
    atomicAdd(&adj[t], s * (1.0f / (float)N1));
}

// --- Kernel 2: center/scale/quantize to fp16 + row sq-norms. One wave per row. ---
__global__ __launch_bounds__(256) void quant_kernel(
    const float* __restrict__ x1, const float* __restrict__ x2,
    const float* __restrict__ adj, const float* __restrict__ ls,
    _Float16* __restrict__ y1, _Float16* __restrict__ y2,
    float* __restrict__ sq1, float* __restrict__ sq2) {
    int wave = threadIdx.x >> 6, lane = threadIdx.x & 63;
    int grow = blockIdx.x * 4 + wave;
    const float* x; _Float16* y; float* sq; int row;
    if (grow < N1) { x = x1; y = y1; sq = sq1; row = grow; }
    else           { x = x2; y = y2; sq = sq2; row = grow - N1; }
    int c = lane * 4;
    f32x4 xv = *(const f32x4*)&x[(size_t)row * DIM + c];
    f32x4 av = *(const f32x4*)&adj[c];
    f32x4 lv = *(const f32x4*)&ls[c];
    half4v h;
    float p = 0.f;
    #pragma unroll
    for (int u = 0; u < 4; ++u) {
        float v = (xv[u] - av[u]) / lv[u];
        _Float16 hh = (_Float16)v;
        h[u] = hh;
        float f = (float)hh;
        p += f * f;
    }
    *(half4v*)&y[(size_t)row * DIM + c] = h;
    #pragma unroll
    for (int off = 32; off > 0; off >>= 1) p += __shfl_down(p, off, 64);
    if (lane == 0) sq[row] = p;
}

// --- Kernel 3: 256x256-tile 8-wave MFMA GEMM, 4-phase/K-step schedule (T1..T5),
//     fused Matern epilogue. ---
// Geometry: BM=BN=256, BK=64, 8 waves (2M x 4N), per-wave output 128x64,
// LDS = 2buf x (256x64 A + 256x64 B) x 2B = 128 KiB -> 1 block/CU by design.
// Swizzle (T2): LDS rows are 128B -> linear layout would be a 16-way bank
// conflict on ds_read_b128 (lanes stride 128B). Fix: 16B chunk s of row r holds
// global k-chunk s^(r&7); LDS dest of global_load_lds stays linear and the
// inverse permutation is applied to the per-lane GLOBAL source address
// (both-sides-or-neither). Reads then spread 8-deep over all 32 banks (optimal).
// Schedule (T3/T4): per K-step: {vmcnt(0)+lgkmcnt(0); barrier} then 4 phases
// {ds_read frags; stage next tile (phases 0-1); setprio(1) 16 MFMA setprio(0);
// barrier}. Loads for tile kt+1 issue in kt's phases 0-1 and are only waited at
// kt+1's top -> ~3 phases of latency cover, never a mid-phase drain.
// MFMA issued as mfma(b, a): D col(lane&15)=M, rows((lane>>4)*4+reg)=4
// consecutive N -> f32x4 epilogue stores (layout verified in R1/R3 runs).
__global__ __launch_bounds__(512, 2) void matern_gemm(
    const _Float16* __restrict__ y1, const _Float16* __restrict__ y2,
    const float* __restrict__ sq1, const float* __restrict__ sq2,
    float* __restrict__ out) {
    __shared__ __align__(16) _Float16 As[2][BM * KH];   // 32 KiB each buf
    __shared__ __align__(16) _Float16 Bs[2][BM * KH];

    const int tid  = threadIdx.x;
    const int wid  = tid >> 6;
    const int lane = tid & 63;

    // T1: XCD-bijective block swizzle (1024 % 8 == 0 -> simple form).
    const int bid = blockIdx.x;
    const int swz = (bid & 7) * 128 + (bid >> 3);
    const int bx = swz & 31;         // N-tile
    const int by = swz >> 5;         // M-tile
    const int row0 = by * BM;        // x1 rows
    const int col0 = bx * BM;        // x2 rows

    const int wr = wid >> 2;         // 0..1  (M half: 128 rows)
    const int wc = wid & 3;          // 0..3  (N quarter: 64 cols)
    const int wm = wr * 128;
    const int wn = wc * 64;
    const int fm = lane & 15;        // frag row within 16-row subtile
    const int q  = lane >> 4;        // k-quarter within K=32 (8 halves)
    const int x0 = q ^ (fm & 7);     // physical chunk for kk=0 (kk=1: x0^4)

    // staging: tile = 256 rows x 8 chunks(16B) = 2048 chunks; 512 thr -> 4
    // chunk-pairs (A+B) per thread per K-step. LDS dest linear: chunk c at c*16.
    // Global source k-chunk = (c&7) ^ (r&7), r = c>>3.
    int srow[4], skh[4];
    #pragma unroll
    for (int l = 0; l < 4; ++l) {
        int c = l * 512 + tid;
        int r = c >> 3, s = c & 7;
        srow[l] = r;
        skh[l] = ((s ^ (r & 7)) * 8);
    }

    f32x4 acc[8][4];
    const f32x4 zero = {0.f, 0.f, 0.f, 0.f};
    #pragma unroll
    for (int i = 0; i < 8; ++i)
        #pragma unroll
        for (int j = 0; j < 4; ++j) acc[i][j] = zero;

    auto stage_pair = [&](int kt, int buf, int l) {
        const int kb = kt * KH;
        const int c16 = (l * 512 + tid) * 16;   // wave-uniform base + lane*16
        async_load16(y1 + (size_t)(row0 + srow[l]) * DIM + kb + skh[l],
                     (char*)As[buf] + c16);
        async_load16(y2 + (size_t)(col0 + srow[l]) * DIM + kb + skh[l],
                     (char*)Bs[buf] + c16);
    };

    // Prologue: stage tile 0 fully.
    #pragma unroll
    for (int l = 0; l < 4; ++l) stage_pair(0, 0, l);

    #pragma unroll
    for (int kt = 0; kt < KSTEPS; ++kt) {
        const int cur = kt & 1;
        // K-step top: tile kt's 8 loads are the only outstanding vmem ops ->
        // vmcnt(0) is an exact counted wait. Barrier also guarantees all waves
        // finished reading buf[cur^1] (their reads completed before their MFMAs).
        asm volatile("s_waitcnt vmcnt(0) lgkmcnt(0)" ::: "memory");
        __builtin_amdgcn_s_barrier();

        const _Float16* Ab = As[cur];
        const _Float16* Bb = Bs[cur];
        half8 a[8];
        #pragma unroll
        for (int kk = 0; kk < 2; ++kk) {
            const int xk = x0 ^ (kk * 4);       // physical chunk this kk
            #pragma unroll
            for (int jh = 0; jh < 2; ++jh) {
                // phase p = kk*2 + jh
                if (jh == 0) {
                    #pragma unroll
                    for (int i = 0; i < 8; ++i)
                        a[i] = *(const half8*)(Ab + (wm + i * 16 + fm) * KH + xk * 8);
                }
                half8 b0 = *(const half8*)(Bb + (wn + (jh * 2 + 0) * 16 + fm) * KH + xk * 8);
                half8 b1 = *(const half8*)(Bb + (wn + (jh * 2 + 1) * 16 + fm) * KH + xk * 8);
                // stage next tile: 4 chunk-pairs in phase 0, 4 in phase 1
                if (kt + 1 < KSTEPS && kk == 0) {
                    stage_pair(kt + 1, cur ^ 1, jh * 2 + 0);
                    stage_pair(kt + 1, cur ^ 1, jh * 2 + 1);
                }
                __builtin_amdgcn_s_setprio(1);
                #pragma unroll
                for (int i = 0; i < 8; ++i) {
                    acc[i][jh * 2 + 0] = __builtin_amdgcn_mfma_f32_16x16x32_f16(b0, a[i], acc[i][jh * 2 + 0], 0, 0, 0);
                    acc[i][jh * 2 + 1] = __builtin_amdgcn_mfma_f32_16x16x32_f16(b1, a[i], acc[i][jh * 2 + 1], 0, 0, 0);
                }
                __builtin_amdgcn_s_setprio(0);
                if (!(kk == 1 && jh == 1))       // last phase: next step's top barrier covers
                    __builtin_amdgcn_s_barrier();
            }
        }
    }

    // Epilogue: swapped-operand C/D layout: col(lane&15)=M, row((lane>>4)*4+reg)=N.
    const int em = fm;               // M within 16-subtile
    const int en = q * 4;            // N base within 16-subtile (4 consecutive via reg)
    float s1v[8];
    #pragma unroll
    for (int i = 0; i < 8; ++i)
        s1v[i] = sq1[row0 + wm + i * 16 + em];
    f32x4 s2v[4];
    #pragma unroll
    for (int j = 0; j < 4; ++j)
        s2v[j] = *(const f32x4*)&sq2[col0 + wn + j * 16 + en];

    #pragma unroll
    for (int i = 0; i < 8; ++i) {
        float* rowp = out + (size_t)(row0 + wm + i * 16 + em) * N2 + (col0 + wn + en);
        #pragma unroll
        for (int j = 0; j < 4; ++j) {   // stores use imm offsets j*64B
            f32x4 o;
            #pragma unroll
            for (int r = 0; r < 4; ++r) {
                float d2 = s1v[i] + s2v[j][r] - 2.0f * acc[i][j][r];
                // fmax(1e-30) subsumes clamp(d2,0) and clamp(dist,1e-15):
                // dist = d2 * rsqrt(d2) >= 1e-15, never NaN.
                d2 = fmaxf(d2, 1e-30f);
                float dist = d2 * __frsqrt_rn(d2);
                float t3 = 1.7320508075688772f * dist;
                o[r] = (1.0f + t3) * __expf(-t3);
            }
            *(f32x4*)&rowp[j * 16] = o;
        }
    }
}

extern "C" void kernel_launch(void* const* d_in, const int* in_sizes, int n_in,
                              void* d_out, int out_size, void* d_ws, size_t ws_size,
                              hipStream_t stream) {
    const float* x1 = (const float*)d_in[0];
    const float* x2 = (const float*)d_in[1];
    const float* ls = (const float*)d_in[2];
    float* out = (float*)d_out;

    // workspace: adj[256]f32 | sq1[8192]f32 | sq2[8192]f32 | y1 fp16 4MB | y2 fp16 4MB
    char* ws = (char*)d_ws;
    float* adj = (float*)ws;
    float* sq1 = (float*)(ws + 1024);
    float* sq2 = (float*)(ws + 1024 + 32768);
    _Float16* y1 = (_Float16*)(ws + 66560);
    _Float16* y2 = (_Float16*)(ws + 66560 + 4194304);

    hipMemsetAsync(adj, 0, 256 * sizeof(float), stream);
    colmean_kernel<<<N1 / 16, 256, 0, stream>>>(x1, adj);
    quant_kernel<<<(N1 + N2) / 4, 256, 0, stream>>>(x1, x2, adj, ls, y1, y2, sq1, sq2);
    matern_gemm<<<dim3((N1 / BM) * (N2 / BM)), 512, 0, stream>>>(y1, y2, sq1, sq2, out);
}